// Round 3
// baseline (245.512 us; speedup 1.0000x reference)
//
#include <hip/hip_runtime.h>
#include <math.h>

#define B_SZ     8192
#define D_IN     2048
#define D_OUT    2048
#define N_NODES  4095
#define STEPS    12         // DEPTH+1
#define N_LEAVES 2048
#define N_SUB    512        // depth-9 subtrees, 4 leaves each
#define CAP      64         // per-leaf bucket capacity (Poisson(4); P(>64)~0)

typedef float f4_t __attribute__((ext_vector_type(4)));

__device__ __forceinline__ float4 nt_load4(const float* p) {
  f4_t v = __builtin_nontemporal_load((const f4_t*)p);
  return make_float4(v.x, v.y, v.z, v.w);
}

// ---------------------------------------------------------------------------
// Kernel 1: transpose W_out (D_OUT x N_NODES) -> Wt (N_NODES x D_OUT).
// (unchanged from round 2 for attribution)
// ---------------------------------------------------------------------------
__global__ __launch_bounds__(256) void transpose_wout(
    const float* __restrict__ W, float* __restrict__ Wt) {
  __shared__ float tile[64][65];
  const int bx = blockIdx.x;
  const int tid = threadIdx.x;
  const int col0 = (bx & 63) * 64;   // N_NODES dim (64 tiles)
  const int row0 = (bx >> 6) * 64;   // D_OUT dim (32 tiles)
  const int r  = tid >> 4;           // 0..15
  const int c4 = (tid & 15) * 4;     // 0..60

  #pragma unroll
  for (int i = 0; i < 4; ++i) {
    const int row = r + i * 16;      // D_OUT-local
    const float* src = W + (size_t)(row0 + row) * N_NODES + col0 + c4;
    if (col0 + c4 + 3 < N_NODES) {
      const float4 v = nt_load4(src);
      tile[c4 + 0][row] = v.x; tile[c4 + 1][row] = v.y;
      tile[c4 + 2][row] = v.z; tile[c4 + 3][row] = v.w;
    } else {
      #pragma unroll
      for (int k = 0; k < 4; ++k)
        tile[c4 + k][row] = (col0 + c4 + k < N_NODES) ? src[k] : 0.0f;
    }
  }
  __syncthreads();
  #pragma unroll
  for (int i = 0; i < 4; ++i) {
    const int rn = r + i * 16;       // N_NODES-local
    const int node = col0 + rn;
    if (node < N_NODES) {
      float4 v;
      v.x = tile[rn][c4 + 0]; v.y = tile[rn][c4 + 1];
      v.z = tile[rn][c4 + 2]; v.w = tile[rn][c4 + 3];
      *(float4*)(Wt + (size_t)node * D_OUT + row0 + c4) = v;
    }
  }
}

// ---------------------------------------------------------------------------
// Kernel 2: routing. One wave/sample, single-child chain.
// KEY CHANGE: explicit load phase (w0..w7 named regs) before the FMA phase.
// Previous build had VGPR=36 -> compiler fused load+FMA, serializing each
// step into ~8 dependent L2 round trips. Batching -> 1 round trip per step.
// FP accumulation order identical to the passing version (bit-exact routing).
// ---------------------------------------------------------------------------
__global__ __launch_bounds__(256) void route_kernel(
    const float* __restrict__ x, const float* __restrict__ W_in,
    int* __restrict__ cnt, int* __restrict__ bucket,
    float* __restrict__ gsc) {
  const int wave = (int)((blockIdx.x * (size_t)blockDim.x + threadIdx.x) >> 6);
  const int lane = threadIdx.x & 63;
  if (wave >= B_SZ) return;

  const float* xbase = x + (size_t)wave * D_IN;
  float4 xv0 = nt_load4(xbase + (lane + 0 * 64) * 4);
  float4 xv1 = nt_load4(xbase + (lane + 1 * 64) * 4);
  float4 xv2 = nt_load4(xbase + (lane + 2 * 64) * 4);
  float4 xv3 = nt_load4(xbase + (lane + 3 * 64) * 4);
  float4 xv4 = nt_load4(xbase + (lane + 4 * 64) * 4);
  float4 xv5 = nt_load4(xbase + (lane + 5 * 64) * 4);
  float4 xv6 = nt_load4(xbase + (lane + 6 * 64) * 4);
  float4 xv7 = nt_load4(xbase + (lane + 7 * 64) * 4);

  int cur = 0;
  #pragma unroll
  for (int d = 0; d < STEPS; ++d) {
    const float4* wr = (const float4*)(W_in + (size_t)cur * D_IN);
    // ---- load phase: 8 independent row chunks, all in flight together ----
    const float4 w0 = wr[lane + 0 * 64];
    const float4 w1 = wr[lane + 1 * 64];
    const float4 w2 = wr[lane + 2 * 64];
    const float4 w3 = wr[lane + 3 * 64];
    const float4 w4 = wr[lane + 4 * 64];
    const float4 w5 = wr[lane + 5 * 64];
    const float4 w6 = wr[lane + 6 * 64];
    const float4 w7 = wr[lane + 7 * 64];
    // ---- FMA phase: same order as the passing kernel ----
    float s = 0.0f;
    s += xv0.x * w0.x + xv0.y * w0.y + xv0.z * w0.z + xv0.w * w0.w;
    s += xv1.x * w1.x + xv1.y * w1.y + xv1.z * w1.z + xv1.w * w1.w;
    s += xv2.x * w2.x + xv2.y * w2.y + xv2.z * w2.z + xv2.w * w2.w;
    s += xv3.x * w3.x + xv3.y * w3.y + xv3.z * w3.z + xv3.w * w3.w;
    s += xv4.x * w4.x + xv4.y * w4.y + xv4.z * w4.z + xv4.w * w4.w;
    s += xv5.x * w5.x + xv5.y * w5.y + xv5.z * w5.z + xv5.w * w5.w;
    s += xv6.x * w6.x + xv6.y * w6.y + xv6.z * w6.z + xv6.w * w6.w;
    s += xv7.x * w7.x + xv7.y * w7.y + xv7.z * w7.z + xv7.w * w7.w;

    #pragma unroll
    for (int off = 32; off > 0; off >>= 1) s += __shfl_xor(s, off);

    if (lane == 0) {
      gsc[wave * STEPS + d] = 0.5f * s * (1.0f + erff(s * 0.70710678118654752f));
      if (d == STEPS - 1) {
        const int leaf = cur - 2047;               // 0..2047
        const int pos = atomicAdd(&cnt[leaf], 1);
        if (pos < CAP) bucket[leaf * CAP + pos] = wave;
      }
    }
    cur = cur * 2 + ((s >= 0.0f) ? 2 : 1);
  }
}

// ---------------------------------------------------------------------------
// Kernel 3: output, max-occupancy variant. 64-col tiles, one float per lane:
// weights = 16 VGPR, total ~55-65 VGPR -> 8 waves/SIMD; grid (128, 32) =
// 4096 blocks -> 32 waves/CU (2x previous). Per wave: one subtree x 64 cols.
// Flattened buckets, coalesced id fetch, 2-deep gsc software pipeline.
// FMA chain order identical to previous passing versions.
// ---------------------------------------------------------------------------
__global__ __launch_bounds__(256) void out_kernel(
    const float* __restrict__ Wt, const int* __restrict__ cnt,
    const int* __restrict__ bucket, const float* __restrict__ gsc,
    float* __restrict__ out) {
  const int sub = blockIdx.x * 4 + (threadIdx.x >> 6);   // 0..511
  const int lane = threadIdx.x & 63;
  const int col = blockIdx.y * 64 + lane;                // one float per lane

  int anc[10];
  {
    int nd = 511 + sub;                 // depth-9 node
    #pragma unroll
    for (int d = 9; d >= 0; --d) { anc[d] = nd; nd = (nd - 1) >> 1; }
  }
  const int p10a = 1023 + 2 * sub;
  const int leaf0n = 2047 + 4 * sub;

  float wa[10], wp[2], wl[4];
  #pragma unroll
  for (int d = 0; d < 10; ++d)
    wa[d] = Wt[(size_t)anc[d] * D_OUT + col];
  #pragma unroll
  for (int k = 0; k < 2; ++k)
    wp[k] = Wt[(size_t)(p10a + k) * D_OUT + col];
  #pragma unroll
  for (int k = 0; k < 4; ++k)
    wl[k] = Wt[(size_t)(leaf0n + k) * D_OUT + col];

  int n0 = cnt[4 * sub + 0]; if (n0 > CAP) n0 = CAP;
  int n1 = cnt[4 * sub + 1]; if (n1 > CAP) n1 = CAP;
  int n2 = cnt[4 * sub + 2]; if (n2 > CAP) n2 = CAP;
  int n3 = cnt[4 * sub + 3]; if (n3 > CAP) n3 = CAP;
  const int p1 = n0, p2 = n0 + n1, p3 = n0 + n1 + n2;
  const int total = p3 + n3;

  for (int base = 0; base < total; base += 64) {
    const int m = (total - base < 64) ? (total - base) : 64;
    // one coalesced fetch of up to 64 sample ids; leaf-local idx in top bits
    int packed = 0;
    {
      const int gi = base + lane;
      if (gi < total) {
        int lc, off;
        if      (gi < p1) { lc = 0; off = 0;  }
        else if (gi < p2) { lc = 1; off = p1; }
        else if (gi < p3) { lc = 2; off = p2; }
        else              { lc = 3; off = p3; }
        const int b = bucket[(4 * sub + lc) * CAP + (gi - off)];
        packed = (lc << 28) | b;
      }
    }
    // 2-deep software pipeline over the m samples
    int pA = __shfl(packed, 0);
    int pB = __shfl(packed, (m > 1) ? 1 : 0);
    const float4* gA = (const float4*)(gsc + (size_t)(pA & 0x0FFFFFFF) * STEPS);
    float4 a0 = gA[0], a1 = gA[1], a2 = gA[2];
    const float4* gB = (const float4*)(gsc + (size_t)(pB & 0x0FFFFFFF) * STEPS);
    float4 b0 = gB[0], b1 = gB[1], b2 = gB[2];

    for (int j = 0; j < m; ++j) {
      int jn = j + 2; if (jn >= m) jn = m - 1;
      const int pC = __shfl(packed, jn);
      const float4* gC = (const float4*)(gsc + (size_t)(pC & 0x0FFFFFFF) * STEPS);
      const float4 t0 = gC[0], t1 = gC[1], t2 = gC[2];

      const int b  = pA & 0x0FFFFFFF;
      const int lc = pA >> 28;
      const float w10 = (lc & 2) ? wp[1] : wp[0];
      const float w11 = (lc & 2) ? ((lc & 1) ? wl[3] : wl[2])
                                 : ((lc & 1) ? wl[1] : wl[0]);
      float acc;
      acc  = a0.x * wa[0];
      acc += a0.y * wa[1];
      acc += a0.z * wa[2];
      acc += a0.w * wa[3];
      acc += a1.x * wa[4];
      acc += a1.y * wa[5];
      acc += a1.z * wa[6];
      acc += a1.w * wa[7];
      acc += a2.x * wa[8];
      acc += a2.y * wa[9];
      acc += a2.z * w10;
      acc += a2.w * w11;
      __builtin_nontemporal_store(acc, out + (size_t)b * D_OUT + col);

      pA = pB; a0 = b0; a1 = b1; a2 = b2;
      pB = pC; b0 = t0; b1 = t1; b2 = t2;
    }
  }
}

// ---------------------------------------------------------------------------
extern "C" void kernel_launch(void* const* d_in, const int* in_sizes, int n_in,
                              void* d_out, int out_size, void* d_ws, size_t ws_size,
                              hipStream_t stream) {
  const float* x     = (const float*)d_in[0];   // (B, D_IN)
  const float* W_in  = (const float*)d_in[1];   // (N_NODES, D_IN)
  const float* W_out = (const float*)d_in[2];   // (D_OUT, N_NODES)
  float* out = (float*)d_out;                   // (B, D_OUT)

  // workspace layout
  char* p = (char*)d_ws;
  float* Wt     = (float*)p;  p += (size_t)N_NODES * D_OUT * sizeof(float);
  int*   cnt    = (int*)p;    p += (size_t)N_LEAVES * sizeof(int);
  int*   bucket = (int*)p;    p += (size_t)N_LEAVES * CAP * sizeof(int);
  float* gsc    = (float*)p;

  hipMemsetAsync(cnt, 0, (size_t)N_LEAVES * sizeof(int), stream);

  route_kernel<<<dim3(B_SZ / 4), dim3(256), 0, stream>>>(
      x, W_in, cnt, bucket, gsc);

  transpose_wout<<<dim3(2048), dim3(256), 0, stream>>>(W_out, Wt);

  out_kernel<<<dim3(N_SUB / 4, 32), dim3(256), 0, stream>>>(
      Wt, cnt, bucket, gsc, out);
}

// Round 4
// 220.026 us; speedup vs baseline: 1.1158x; 1.1158x over previous
//
#include <hip/hip_runtime.h>
#include <math.h>

#define B_SZ     8192
#define D_IN     2048
#define D_OUT    2048
#define N_NODES  4095
#define STEPS    12         // DEPTH+1
#define N_LEAVES 2048
#define N_SUB    512        // depth-9 subtrees, 4 leaves each
#define CAP      64         // per-leaf bucket capacity (Poisson(4); P(>64)~0)

typedef float f4 __attribute__((ext_vector_type(4)));

__device__ __forceinline__ f4 nt_load(const float* p) {
  return __builtin_nontemporal_load((const f4*)p);
}

// ---------------------------------------------------------------------------
// Kernel 1: transpose W_out (D_OUT x N_NODES) -> Wt (N_NODES x D_OUT).
// ---------------------------------------------------------------------------
__global__ __launch_bounds__(256) void transpose_wout(
    const float* __restrict__ W, float* __restrict__ Wt) {
  __shared__ float tile[64][65];
  const int bx = blockIdx.x;
  const int tid = threadIdx.x;
  const int col0 = (bx & 63) * 64;   // N_NODES dim (64 tiles)
  const int row0 = (bx >> 6) * 64;   // D_OUT dim (32 tiles)
  const int r  = tid >> 4;           // 0..15
  const int c4 = (tid & 15) * 4;     // 0..60

  #pragma unroll
  for (int i = 0; i < 4; ++i) {
    const int row = r + i * 16;      // D_OUT-local
    const float* src = W + (size_t)(row0 + row) * N_NODES + col0 + c4;
    if (col0 + c4 + 3 < N_NODES) {
      const float4 v = *(const float4*)src;
      tile[c4 + 0][row] = v.x; tile[c4 + 1][row] = v.y;
      tile[c4 + 2][row] = v.z; tile[c4 + 3][row] = v.w;
    } else {
      #pragma unroll
      for (int k = 0; k < 4; ++k)
        tile[c4 + k][row] = (col0 + c4 + k < N_NODES) ? src[k] : 0.0f;
    }
  }
  __syncthreads();
  #pragma unroll
  for (int i = 0; i < 4; ++i) {
    const int rn = r + i * 16;       // N_NODES-local
    const int node = col0 + rn;
    if (node < N_NODES) {
      float4 v;
      v.x = tile[rn][c4 + 0]; v.y = tile[rn][c4 + 1];
      v.z = tile[rn][c4 + 2]; v.w = tile[rn][c4 + 3];
      *(float4*)(Wt + (size_t)node * D_OUT + row0 + c4) = v;
    }
  }
}

// ---------------------------------------------------------------------------
// Kernel 2: routing. One wave/sample, single-child chain.
// Compiler-proof batching: W chunks go through an empty asm with "+v"
// constraints -> all 8 loads must complete before use (ONE cache round-trip
// per step) and values are opaque (no refetch). Same pin holds the 8 x
// chunks resident for the whole kernel (previous builds: VGPR=36 meant x was
// being re-read from cache every step and W loads serialized).
// ---------------------------------------------------------------------------
__global__ __launch_bounds__(256, 5) void route_kernel(
    const float* __restrict__ x, const float* __restrict__ W_in,
    int* __restrict__ cnt, int* __restrict__ bucket,
    float* __restrict__ gsc) {
  const int wave = (int)((blockIdx.x * (size_t)blockDim.x + threadIdx.x) >> 6);
  const int lane = threadIdx.x & 63;
  if (wave >= B_SZ) return;

  const float* xbase = x + (size_t)wave * D_IN;
  f4 xv0 = nt_load(xbase + (lane + 0 * 64) * 4);
  f4 xv1 = nt_load(xbase + (lane + 1 * 64) * 4);
  f4 xv2 = nt_load(xbase + (lane + 2 * 64) * 4);
  f4 xv3 = nt_load(xbase + (lane + 3 * 64) * 4);
  f4 xv4 = nt_load(xbase + (lane + 4 * 64) * 4);
  f4 xv5 = nt_load(xbase + (lane + 5 * 64) * 4);
  f4 xv6 = nt_load(xbase + (lane + 6 * 64) * 4);
  f4 xv7 = nt_load(xbase + (lane + 7 * 64) * 4);
  asm volatile("" : "+v"(xv0), "+v"(xv1), "+v"(xv2), "+v"(xv3),
                    "+v"(xv4), "+v"(xv5), "+v"(xv6), "+v"(xv7));

  int cur = 0;
  #pragma unroll
  for (int d = 0; d < STEPS; ++d) {
    const f4* wr = (const f4*)(W_in + (size_t)cur * D_IN);
    f4 w0 = wr[lane + 0 * 64];
    f4 w1 = wr[lane + 1 * 64];
    f4 w2 = wr[lane + 2 * 64];
    f4 w3 = wr[lane + 3 * 64];
    f4 w4 = wr[lane + 4 * 64];
    f4 w5 = wr[lane + 5 * 64];
    f4 w6 = wr[lane + 6 * 64];
    f4 w7 = wr[lane + 7 * 64];
    asm volatile("" : "+v"(w0), "+v"(w1), "+v"(w2), "+v"(w3),
                      "+v"(w4), "+v"(w5), "+v"(w6), "+v"(w7));
    // FMA phase: accumulation order identical to all passing versions
    float s = 0.0f;
    s += xv0.x * w0.x + xv0.y * w0.y + xv0.z * w0.z + xv0.w * w0.w;
    s += xv1.x * w1.x + xv1.y * w1.y + xv1.z * w1.z + xv1.w * w1.w;
    s += xv2.x * w2.x + xv2.y * w2.y + xv2.z * w2.z + xv2.w * w2.w;
    s += xv3.x * w3.x + xv3.y * w3.y + xv3.z * w3.z + xv3.w * w3.w;
    s += xv4.x * w4.x + xv4.y * w4.y + xv4.z * w4.z + xv4.w * w4.w;
    s += xv5.x * w5.x + xv5.y * w5.y + xv5.z * w5.z + xv5.w * w5.w;
    s += xv6.x * w6.x + xv6.y * w6.y + xv6.z * w6.z + xv6.w * w6.w;
    s += xv7.x * w7.x + xv7.y * w7.y + xv7.z * w7.z + xv7.w * w7.w;

    #pragma unroll
    for (int off = 32; off > 0; off >>= 1) s += __shfl_xor(s, off);

    if (lane == 0) {
      gsc[wave * STEPS + d] = 0.5f * s * (1.0f + erff(s * 0.70710678118654752f));
      if (d == STEPS - 1) {
        const int leaf = cur - 2047;               // 0..2047
        const int pos = atomicAdd(&cnt[leaf], 1);
        if (pos < CAP) bucket[leaf * CAP + pos] = wave;
      }
    }
    cur = cur * 2 + ((s >= 0.0f) ? 2 : 1);
  }
}

// ---------------------------------------------------------------------------
// Kernel 3: output (round-2 float4/256-col form — measured best). 4 waves/
// block, one subtree per wave. Weight preamble batched+pinned via asm (one
// round trip, no refetch). Flattened buckets, coalesced id fetch, 2-deep gsc
// software pipeline. FMA chain order identical to passing versions.
// ---------------------------------------------------------------------------
__global__ __launch_bounds__(256) void out_kernel(
    const float* __restrict__ Wt, const int* __restrict__ cnt,
    const int* __restrict__ bucket, const float* __restrict__ gsc,
    float* __restrict__ out) {
  const int sub = blockIdx.x * 4 + (threadIdx.x >> 6);   // 0..511
  const int lane = threadIdx.x & 63;
  const int col = blockIdx.y * 256 + lane * 4;

  int anc[10];
  {
    int nd = 511 + sub;                 // depth-9 node
    #pragma unroll
    for (int d = 9; d >= 0; --d) { anc[d] = nd; nd = (nd - 1) >> 1; }
  }
  const int p10a = 1023 + 2 * sub;
  const int leaf0n = 2047 + 4 * sub;

  f4 wa0 = *(const f4*)(Wt + (size_t)anc[0] * D_OUT + col);
  f4 wa1 = *(const f4*)(Wt + (size_t)anc[1] * D_OUT + col);
  f4 wa2 = *(const f4*)(Wt + (size_t)anc[2] * D_OUT + col);
  f4 wa3 = *(const f4*)(Wt + (size_t)anc[3] * D_OUT + col);
  f4 wa4 = *(const f4*)(Wt + (size_t)anc[4] * D_OUT + col);
  f4 wa5 = *(const f4*)(Wt + (size_t)anc[5] * D_OUT + col);
  f4 wa6 = *(const f4*)(Wt + (size_t)anc[6] * D_OUT + col);
  f4 wa7 = *(const f4*)(Wt + (size_t)anc[7] * D_OUT + col);
  f4 wa8 = *(const f4*)(Wt + (size_t)anc[8] * D_OUT + col);
  f4 wa9 = *(const f4*)(Wt + (size_t)anc[9] * D_OUT + col);
  f4 wp0 = *(const f4*)(Wt + (size_t)(p10a + 0) * D_OUT + col);
  f4 wp1 = *(const f4*)(Wt + (size_t)(p10a + 1) * D_OUT + col);
  f4 wl0 = *(const f4*)(Wt + (size_t)(leaf0n + 0) * D_OUT + col);
  f4 wl1 = *(const f4*)(Wt + (size_t)(leaf0n + 1) * D_OUT + col);
  f4 wl2 = *(const f4*)(Wt + (size_t)(leaf0n + 2) * D_OUT + col);
  f4 wl3 = *(const f4*)(Wt + (size_t)(leaf0n + 3) * D_OUT + col);
  asm volatile("" : "+v"(wa0), "+v"(wa1), "+v"(wa2), "+v"(wa3), "+v"(wa4),
                    "+v"(wa5), "+v"(wa6), "+v"(wa7), "+v"(wa8), "+v"(wa9),
                    "+v"(wp0), "+v"(wp1),
                    "+v"(wl0), "+v"(wl1), "+v"(wl2), "+v"(wl3));

  int n0 = cnt[4 * sub + 0]; if (n0 > CAP) n0 = CAP;
  int n1 = cnt[4 * sub + 1]; if (n1 > CAP) n1 = CAP;
  int n2 = cnt[4 * sub + 2]; if (n2 > CAP) n2 = CAP;
  int n3 = cnt[4 * sub + 3]; if (n3 > CAP) n3 = CAP;
  const int p1 = n0, p2 = n0 + n1, p3 = n0 + n1 + n2;
  const int total = p3 + n3;

  for (int base = 0; base < total; base += 64) {
    const int m = (total - base < 64) ? (total - base) : 64;
    // one coalesced fetch of up to 64 sample ids; leaf-local idx in top bits
    int packed = 0;
    {
      const int gi = base + lane;
      if (gi < total) {
        int lc, off;
        if      (gi < p1) { lc = 0; off = 0;  }
        else if (gi < p2) { lc = 1; off = p1; }
        else if (gi < p3) { lc = 2; off = p2; }
        else              { lc = 3; off = p3; }
        const int b = bucket[(4 * sub + lc) * CAP + (gi - off)];
        packed = (lc << 28) | b;
      }
    }
    // 2-deep software pipeline over the m samples
    int pA = __shfl(packed, 0);
    int pB = __shfl(packed, (m > 1) ? 1 : 0);
    const float4* gA = (const float4*)(gsc + (size_t)(pA & 0x0FFFFFFF) * STEPS);
    float4 a0 = gA[0], a1 = gA[1], a2 = gA[2];
    const float4* gB = (const float4*)(gsc + (size_t)(pB & 0x0FFFFFFF) * STEPS);
    float4 b0 = gB[0], b1 = gB[1], b2 = gB[2];

    for (int j = 0; j < m; ++j) {
      int jn = j + 2; if (jn >= m) jn = m - 1;
      const int pC = __shfl(packed, jn);
      const float4* gC = (const float4*)(gsc + (size_t)(pC & 0x0FFFFFFF) * STEPS);
      const float4 t0 = gC[0], t1 = gC[1], t2 = gC[2];

      const int b  = pA & 0x0FFFFFFF;
      const int lc = pA >> 28;
      const f4 w10 = (lc & 2) ? wp1 : wp0;
      const f4 w11 = (lc & 2) ? ((lc & 1) ? wl3 : wl2)
                              : ((lc & 1) ? wl1 : wl0);
      f4 acc;
      acc.x = a0.x * wa0.x; acc.y = a0.x * wa0.y;
      acc.z = a0.x * wa0.z; acc.w = a0.x * wa0.w;
      acc.x += a0.y * wa1.x; acc.y += a0.y * wa1.y;
      acc.z += a0.y * wa1.z; acc.w += a0.y * wa1.w;
      acc.x += a0.z * wa2.x; acc.y += a0.z * wa2.y;
      acc.z += a0.z * wa2.z; acc.w += a0.z * wa2.w;
      acc.x += a0.w * wa3.x; acc.y += a0.w * wa3.y;
      acc.z += a0.w * wa3.z; acc.w += a0.w * wa3.w;
      acc.x += a1.x * wa4.x; acc.y += a1.x * wa4.y;
      acc.z += a1.x * wa4.z; acc.w += a1.x * wa4.w;
      acc.x += a1.y * wa5.x; acc.y += a1.y * wa5.y;
      acc.z += a1.y * wa5.z; acc.w += a1.y * wa5.w;
      acc.x += a1.z * wa6.x; acc.y += a1.z * wa6.y;
      acc.z += a1.z * wa6.z; acc.w += a1.z * wa6.w;
      acc.x += a1.w * wa7.x; acc.y += a1.w * wa7.y;
      acc.z += a1.w * wa7.z; acc.w += a1.w * wa7.w;
      acc.x += a2.x * wa8.x; acc.y += a2.x * wa8.y;
      acc.z += a2.x * wa8.z; acc.w += a2.x * wa8.w;
      acc.x += a2.y * wa9.x; acc.y += a2.y * wa9.y;
      acc.z += a2.y * wa9.z; acc.w += a2.y * wa9.w;
      acc.x += a2.z * w10.x; acc.y += a2.z * w10.y;
      acc.z += a2.z * w10.z; acc.w += a2.z * w10.w;
      acc.x += a2.w * w11.x; acc.y += a2.w * w11.y;
      acc.z += a2.w * w11.z; acc.w += a2.w * w11.w;
      __builtin_nontemporal_store(acc, (f4*)(out + (size_t)b * D_OUT + col));

      pA = pB; a0 = b0; a1 = b1; a2 = b2;
      pB = pC; b0 = t0; b1 = t1; b2 = t2;
    }
  }
}

// ---------------------------------------------------------------------------
extern "C" void kernel_launch(void* const* d_in, const int* in_sizes, int n_in,
                              void* d_out, int out_size, void* d_ws, size_t ws_size,
                              hipStream_t stream) {
  const float* x     = (const float*)d_in[0];   // (B, D_IN)
  const float* W_in  = (const float*)d_in[1];   // (N_NODES, D_IN)
  const float* W_out = (const float*)d_in[2];   // (D_OUT, N_NODES)
  float* out = (float*)d_out;                   // (B, D_OUT)

  // workspace layout
  char* p = (char*)d_ws;
  float* Wt     = (float*)p;  p += (size_t)N_NODES * D_OUT * sizeof(float);
  int*   cnt    = (int*)p;    p += (size_t)N_LEAVES * sizeof(int);
  int*   bucket = (int*)p;    p += (size_t)N_LEAVES * CAP * sizeof(int);
  float* gsc    = (float*)p;

  hipMemsetAsync(cnt, 0, (size_t)N_LEAVES * sizeof(int), stream);

  route_kernel<<<dim3(B_SZ / 4), dim3(256), 0, stream>>>(
      x, W_in, cnt, bucket, gsc);

  transpose_wout<<<dim3(2048), dim3(256), 0, stream>>>(W_out, Wt);

  out_kernel<<<dim3(N_SUB / 4, 8), dim3(256), 0, stream>>>(
      Wt, cnt, bucket, gsc, out);
}